// Round 9
// baseline (723.335 us; speedup 1.0000x reference)
//
#include <hip/hip_runtime.h>
#include <hip/hip_bf16.h>

#define NN 50000
#define EE 640000
#define NEG 0.2f
#define CAP 64           // per-segment cache; degree ~ Poisson(12.8), P(k>=64) ~ 1e-24

#define BSH 9                          // 512 dsts per bucket
#define NBKT 98                        // ceil(NN/512)
#define FCAP 7168                      // LDS record stage in bucket_final
#define CHUNKA 8192
#define PA_B 79                        // ceil(EE/CHUNKA)

struct Ptr8 { const int* p[8]; };
struct MArgs { const float* w[8]; const float* al[8]; const float* ar[8]; };

struct SegArg {
    const int* starts;
    const int* counts;
    const unsigned short* srt;
    const float* adst;
    const float* asrc;
    const unsigned short* feats;
    const float* pw;
    int pwi;
    int hasLoop;
};

struct ProjArgs {
    const float* in;
    const unsigned short* Wp0; const unsigned short* Wp1;
    const float* M0; const float* M1;
    unsigned short* ob0; unsigned short* ob1;
    float4* dl0; float4* dr0; float4* dl1; float4* dr1;
};

struct EmbArgs {
    const float* x; const float* Wt; const float* g; const float* b;
    const float* pw; const float* sb; float* F; float* C;
};

typedef __attribute__((ext_vector_type(8))) short short8;
typedef __attribute__((ext_vector_type(8))) unsigned short ushort8;
typedef __attribute__((ext_vector_type(4))) float floatx4;

__device__ __forceinline__ unsigned short f2bf(float x) {
    unsigned b = __float_as_uint(x);
    b = b + 0x7fffu + ((b >> 16) & 1u);   // RNE
    return (unsigned short)(b >> 16);
}

__device__ __forceinline__ float4 leakyexp4(float4 ad, float4 as) {
    float v0 = ad.x + as.x, v1 = ad.y + as.y, v2 = ad.z + as.z, v3 = ad.w + as.w;
    v0 = v0 > 0.f ? v0 : NEG * v0;
    v1 = v1 > 0.f ? v1 : NEG * v1;
    v2 = v2 > 0.f ? v2 : NEG * v2;
    v3 = v3 > 0.f ? v3 : NEG * v3;
    return make_float4(__expf(v0), __expf(v1), __expf(v2), __expf(v3));
}

// ---------------- merged one-shot prep: transpose emb W + make M + fragment-order W ----
__global__ void prep_all(const float* __restrict__ wev, const float* __restrict__ wec,
                         float* __restrict__ Wt, MArgs a, float* __restrict__ Mbuf,
                         unsigned short* __restrict__ Wbf)
{
    int b = blockIdx.x;
    if (b < 64) {
        int i = b * 256 + threadIdx.x;
        if (i < 8192) { Wt[i] = wev[(i & 127) * 64 + (i >> 7)]; }
        else { int j = i - 8192; Wt[i] = wec[(j & 127) * 64 + (j >> 7)]; }
        return;
    }
    if (b < 128) {
        int tid = (b - 64) * 256 + threadIdx.x;   // 0..16383
        int w = tid >> 11;
        int idx = tid & 2047;
        int tile = idx >> 6;          // ct*4 + kc
        int lane = idx & 63;
        int ct = tile >> 2, kc = tile & 3;
        int n = ct * 16 + (lane & 15);
        int k0 = kc * 32 + (lane >> 4) * 8;
        const float* src = a.w[w] + n * 128 + k0;
        short8 v;
#pragma unroll
        for (int j = 0; j < 8; j++) v[j] = (short)f2bf(src[j]);
        *(short8*)&Wbf[(size_t)tid * 8] = v;
        return;
    }
    {   // make_M: M[p] = W_p^T @ [attL | attR]
        int w = b - 128;
        const float* W  = a.w[w];
        const float* AL = a.al[w];
        const float* AR = a.ar[w];
        for (int e = threadIdx.x; e < 1024; e += 256) {
            int k = e >> 3, h = e & 7;
            const float* att = (h < 4) ? AL : AR;
            int hh = h & 3;
            float s = 0.f;
            for (int c = 0; c < 128; c++) s += W[c * 128 + k] * att[c * 4 + hh];
            Mbuf[w * 1024 + e] = s;
        }
    }
}

// ---------------- device bodies shared by fused kernels ----------------

// embed+LN for 16 rows, 256 threads (two 128-thread halves of 8 rows each)
__device__ __forceinline__ void embed_body16(const EmbArgs& E, int blk, char* smem)
{
    float (*lx)[8][64]  = (float(*)[8][64])smem;            // [2][8][64] = 4096 B
    float (*red)[2][8][2] = (float(*)[2][8][2])(smem + 4096); // [2][2][8][2] = 512 B
    int t = threadIdx.x;
    int subh = t >> 7, c = t & 127;
    int n0 = blk * 16 + subh * 8;
    for (int tt = c; tt < 8 * 64; tt += 128)
        lx[subh][tt >> 6][tt & 63] = E.x[(size_t)(n0 + (tt >> 6)) * 64 + (tt & 63)];
    __syncthreads();
    float acc[8];
#pragma unroll
    for (int m = 0; m < 8; m++) acc[m] = 0.f;
    for (int k = 0; k < 64; k++) {
        float w = E.Wt[k * 128 + c];
#pragma unroll
        for (int m = 0; m < 8; m++) acc[m] += lx[subh][m][k] * w;
    }
    int lane = c & 63, wv = c >> 6;
#pragma unroll
    for (int m = 0; m < 8; m++) {
        float s1 = acc[m], s2 = acc[m] * acc[m];
        for (int off = 32; off; off >>= 1) { s1 += __shfl_xor(s1, off); s2 += __shfl_xor(s2, off); }
        if (lane == 0) { red[subh][wv][m][0] = s1; red[subh][wv][m][1] = s2; }
    }
    __syncthreads();
    float biassum = E.pw[0] * E.sb[c] + E.pw[1] * E.sb[128 + c];
    float gg = E.g[c], bb = E.b[c];
#pragma unroll
    for (int m = 0; m < 8; m++) {
        float s1 = red[subh][0][m][0] + red[subh][1][m][0];
        float s2 = red[subh][0][m][1] + red[subh][1][m][1];
        float mu  = s1 * (1.f / 128.f);
        float var = s2 * (1.f / 128.f) - mu * mu;
        float inv = rsqrtf(var + 1e-5f);
        float v = acc[m];
        size_t idx = (size_t)(n0 + m) * 128 + c;
        E.F[idx] = v + biassum;
        E.C[idx] = (v - mu) * inv * gg + bb;
    }
}

__device__ __forceinline__ void count_body(const Ptr8& dst, int idx, int* __restrict__ bcnt,
                                           char* smem)
{
    int* h = (int*)smem;
    int l = idx / PA_B, cb = idx % PA_B;
    const int* dp = dst.p[l];
    for (int i = threadIdx.x; i < NBKT; i += 256) h[i] = 0;
    __syncthreads();
    int e0 = cb * CHUNKA;
    for (int i = threadIdx.x; i < CHUNKA; i += 256) {
        int e = e0 + i;
        if (e < EE) atomicAdd(&h[dp[e] >> BSH], 1);
    }
    __syncthreads();
    for (int i = threadIdx.x; i < NBKT; i += 256)
        if (h[i]) atomicAdd(&bcnt[l * NBKT + i], h[i]);
}

__device__ __forceinline__ void place_body(const Ptr8& src, const Ptr8& dst, int idx,
                                           int* __restrict__ bcur, unsigned* __restrict__ recs,
                                           char* smem)
{
    int* h = (int*)smem;
    int* base = h + 128;
    int l = idx / PA_B, cb = idx % PA_B;
    const int* sp = src.p[l];
    const int* dp = dst.p[l];
    for (int i = threadIdx.x; i < NBKT; i += 256) h[i] = 0;
    __syncthreads();
    int e0 = cb * CHUNKA;
    for (int i = threadIdx.x; i < CHUNKA; i += 256) {
        int e = e0 + i;
        if (e < EE) atomicAdd(&h[dp[e] >> BSH], 1);
    }
    __syncthreads();
    for (int i = threadIdx.x; i < NBKT; i += 256) {
        int c = h[i];
        base[i] = c ? atomicAdd(&bcur[l * NBKT + i], c) : 0;
        h[i] = 0;
    }
    __syncthreads();
    unsigned* rl = recs + (size_t)l * EE;
    for (int i = threadIdx.x; i < CHUNKA; i += 256) {
        int e = e0 + i;
        if (e >= EE) continue;
        int d = dp[e];
        int b = d >> BSH;
        int pos = base[b] + atomicAdd(&h[b], 1);
        rl[pos] = ((unsigned)sp[e] << 16) | (unsigned)d;
    }
}

__device__ __forceinline__ void proj_body(const ProjArgs& P, int blk, float* ML)
{
    int t = threadIdx.x;
    for (int i = t; i < 2048; i += 256) ML[i] = (i < 1024) ? P.M0[i] : P.M1[i - 1024];
    __syncthreads();

    int w = t >> 6, lane = t & 63;
    int rg = w & 1, chh = w >> 1;
    int ln = lane & 15, quad = lane >> 4;
    int rbase = blk * 32 + rg * 16;
    int row = rbase + ln;
    int arow = (row < NN) ? row : (NN - 1);
    const float* MLh = &ML[chh * 1024];

    short8 afrag[4];
    float p[8];
#pragma unroll
    for (int h = 0; h < 8; h++) p[h] = 0.f;
#pragma unroll
    for (int kc = 0; kc < 4; kc++) {
        int k0 = kc * 32 + quad * 8;
        const float* ap = P.in + (size_t)arow * 128 + k0;
        float av[8];
#pragma unroll
        for (int j = 0; j < 8; j++) av[j] = ap[j];
#pragma unroll
        for (int j = 0; j < 8; j++) {
            afrag[kc][j] = (short)f2bf(av[j]);
            const float* mrow = &MLh[(k0 + j) * 8];
#pragma unroll
            for (int h = 0; h < 8; h++) p[h] += av[j] * mrow[h];
        }
    }
#pragma unroll
    for (int h = 0; h < 8; h++) {
        p[h] += __shfl_xor(p[h], 16);
        p[h] += __shfl_xor(p[h], 32);
    }
    if (quad == 0 && row < NN) {
        if (chh == 0) {
            P.dl0[row] = make_float4(p[0], p[1], p[2], p[3]);
            P.dr0[row] = make_float4(p[4], p[5], p[6], p[7]);
        } else {
            P.dl1[row] = make_float4(p[0], p[1], p[2], p[3]);
            P.dr1[row] = make_float4(p[4], p[5], p[6], p[7]);
        }
    }

    // ---- phase 0: MFMA with Wp0 (this wave's 4 ct tiles) ----
#pragma unroll
    for (int cti = 0; cti < 4; cti++) {
        int ct = chh * 4 + cti;
        floatx4 acc = {0.f, 0.f, 0.f, 0.f};
#pragma unroll
        for (int kc = 0; kc < 4; kc++) {
            short8 bfr = *(const short8*)&P.Wp0[(size_t)((ct * 4 + kc) * 64 + lane) * 8];
            acc = __builtin_amdgcn_mfma_f32_16x16x32_bf16(afrag[kc], bfr, acc, 0, 0, 0);
        }
#pragma unroll
        for (int r = 0; r < 4; r++) {
            int rr = rbase + quad * 4 + r;
            if (rr < NN) P.ob0[(size_t)rr * 128 + ct * 16 + ln] = f2bf(acc[r]);
        }
    }
    // ---- phase 1: MFMA with Wp1 ----
#pragma unroll
    for (int cti = 0; cti < 4; cti++) {
        int ct = chh * 4 + cti;
        floatx4 acc = {0.f, 0.f, 0.f, 0.f};
#pragma unroll
        for (int kc = 0; kc < 4; kc++) {
            short8 bfr = *(const short8*)&P.Wp1[(size_t)((ct * 4 + kc) * 64 + lane) * 8];
            acc = __builtin_amdgcn_mfma_f32_16x16x32_bf16(afrag[kc], bfr, acc, 0, 0, 0);
        }
#pragma unroll
        for (int r = 0; r < 4; r++) {
            int rr = rbase + quad * 4 + r;
            if (rr < NN) P.ob1[(size_t)rr * 128 + ct * 16 + ln] = f2bf(acc[r]);
        }
    }
}

// ---------------- fused: embed_ln (both sides) || bucket_count ----------------
__global__ __launch_bounds__(256) void fused_embed_count(
    EmbArgs Ea, EmbArgs Eb, int nbE, Ptr8 dst, int* __restrict__ bcnt)
{
    __shared__ __align__(16) char smem[4608];
    int b = blockIdx.x;
    if (b < 2 * nbE) {
        int side = b >= nbE;
        embed_body16(side ? Eb : Ea, b - (side ? nbE : 0), smem);
    } else {
        count_body(dst, b - 2 * nbE, bcnt, smem);
    }
}

// ---------------- fused: self projections (2 pairs) || bucket_place ----------------
__global__ __launch_bounds__(256) void fused_proj_place(
    ProjArgs Pa, ProjArgs Pb, int nbP,
    Ptr8 src, Ptr8 dst, int* __restrict__ bcur, unsigned* __restrict__ recs)
{
    __shared__ __align__(16) char smem[8448];
    int b = blockIdx.x;
    if (b < 2 * nbP) {
        int half = b >= nbP;
        proj_body(half ? Pb : Pa, b - (half ? nbP : 0), (float*)smem);
    } else {
        place_body(src, dst, b - 2 * nbP, bcur, recs, smem);
    }
}

// ---------------- standalone pair projection (cross phase) ----------------
__global__ __launch_bounds__(256) void mfma_proj2(ProjArgs Pa, ProjArgs Pb, int nb)
{
    __shared__ __align__(16) float ML[2112];
    int half = blockIdx.x >= nb;
    proj_body(half ? Pb : Pa, blockIdx.x - (half ? nb : 0), ML);
}

// ================= bucket sort: scan + final =================
__global__ void bucket_scan(const int* __restrict__ bcnt, int* __restrict__ bstart,
                            int* __restrict__ bcur)
{
    __shared__ int sh[NBKT];
    int l = blockIdx.x;
    for (int i = threadIdx.x; i < NBKT; i += 256) sh[i] = bcnt[l * NBKT + i];
    __syncthreads();
    if (threadIdx.x == 0) {
        int acc = 0;
        for (int i = 0; i < NBKT; i++) { int t = sh[i]; sh[i] = acc; acc += t; }
    }
    __syncthreads();
    for (int i = threadIdx.x; i < NBKT; i += 256) {
        bstart[l * (NBKT + 1) + i] = sh[i];
        bcur[l * NBKT + i] = sh[i];
    }
    if (threadIdx.x == 0) bstart[l * (NBKT + 1) + NBKT] = EE;
}

// one block per 512-dst bucket: stage recs in LDS, parallel scan, exact placement
__global__ __launch_bounds__(256) void bucket_final(
    const unsigned* __restrict__ recs, const int* __restrict__ bstart,
    int* __restrict__ starts8, int* __restrict__ counts8,
    unsigned short* __restrict__ sortedU)
{
    __shared__ unsigned R[FCAP];
    __shared__ int cnt[512];
    __shared__ int cur[512];
    __shared__ int psum[256];
    int l = blockIdx.x / NBKT, b = blockIdx.x % NBKT;
    int d0 = b << BSH;
    int nd = min(512, NN - d0);
    int ebase = bstart[l * (NBKT + 1) + b];
    int ecnt  = bstart[l * (NBKT + 1) + b + 1] - ebase;
    const unsigned* rp = recs + (size_t)l * EE + ebase;
    int t = threadIdx.x;
    bool inLds = (ecnt <= FCAP);

    for (int i = t; i < 512; i += 256) cnt[i] = 0;
    __syncthreads();
    for (int i = t; i < ecnt; i += 256) {
        unsigned r = rp[i];
        if (inLds) R[i] = r;
        atomicAdd(&cnt[(r & 0xffffu) - d0], 1);
    }
    __syncthreads();
    // exclusive scan of cnt[512]: pairwise partials + 256-ladder
    int s0 = cnt[2 * t] + cnt[2 * t + 1];
    psum[t] = s0;
    __syncthreads();
    for (int off = 1; off < 256; off <<= 1) {
        int x = (t >= off) ? psum[t - off] : 0;
        __syncthreads();
        psum[t] += x;
        __syncthreads();
    }
    int excl = psum[t] - s0;
    cur[2 * t] = excl;
    cur[2 * t + 1] = excl + cnt[2 * t];
    __syncthreads();
    for (int i = t; i < nd; i += 256) {
        starts8[l * NN + d0 + i] = ebase + cur[i];
        counts8[l * NN + d0 + i] = cnt[i];
    }
    __syncthreads();
    unsigned short* so = sortedU + (size_t)l * EE + ebase;
    for (int i = t; i < ecnt; i += 256) {
        unsigned r = inLds ? R[i] : rp[i];
        int dloc = (int)(r & 0xffffu) - d0;
        int pos = atomicAdd(&cur[dloc], 1);
        so[pos] = (unsigned short)(r >> 16);
    }
}

// ---------------- fused pair aggregation: 16-lane groups, reg-held exp, 4-deep gather ----
// (R8 structure, unchanged: best measured. One block per 8-dst chunk, two
// independent pair-sets per launch; no __syncthreads.)
__global__ __launch_bounds__(256, 4) void agg_fused2(
    SegArg A0, SegArg B0, float* __restrict__ acc0,
    SegArg A1, SegArg B1, float* __restrict__ acc1,
    const float* __restrict__ bias0, const float* __restrict__ bias1,
    int nb, int mode)
{
    __shared__ float          wSh[16][CAP + 1];   // stride 65 words (bank-padded)
    __shared__ unsigned short sSh[16][CAP + 2];   // stride 33 words

    int t = threadIdx.x;
    int gid = t >> 4, sub = t & 15;
    int seg = gid & 1;
    int half = blockIdx.x >= nb;
    int blk = blockIdx.x - (half ? nb : 0);
    int d = blk * 8 + (gid >> 1);

    const SegArg S = half ? (seg ? B1 : A1) : (seg ? B0 : A0);
    float* acc = half ? acc1 : acc0;

    int base = S.starts[d];
    int k = S.counts[d];
    int kTot = k + S.hasLoop;
    int kW = kTot < CAP ? kTot : CAP;

    float4 ad = *(const float4*)(S.adst + (size_t)d * 4);

    // ---- pass 1a: src ids -> LDS immediately ----
    int ia = sub, ib = sub + 16, ic = sub + 32, id_ = sub + 48;
    int s0 = d, s1 = d, s2 = d, s3 = d;
    if (ia < kTot) { if (ia < k) s0 = (int)S.srt[base + ia]; sSh[gid][ia] = (unsigned short)s0; }
    if (ib < kTot) { if (ib < k) s1 = (int)S.srt[base + ib]; sSh[gid][ib] = (unsigned short)s1; }
    if (ic < kTot) { if (ic < k) s2 = (int)S.srt[base + ic]; sSh[gid][ic] = (unsigned short)s2; }
    if (id_ < kTot){ if (id_ < k) s3 = (int)S.srt[base + id_]; sSh[gid][id_] = (unsigned short)s3; }

    // ---- pass 1b: issue asrc loads ----
    float4 as0 = {0,0,0,0}, as1 = {0,0,0,0}, as2 = {0,0,0,0}, as3 = {0,0,0,0};
    if (ia < kTot)  as0 = *(const float4*)(S.asrc + (size_t)s0 * 4);
    if (ib < kTot)  as1 = *(const float4*)(S.asrc + (size_t)s1 * 4);
    if (ic < kTot)  as2 = *(const float4*)(S.asrc + (size_t)s2 * 4);
    if (id_ < kTot) as3 = *(const float4*)(S.asrc + (size_t)s3 * 4);

    // ---- prefetch first 4 gather rows (independent of softmax) ----
    const unsigned short* fbase = S.feats + sub * 8;
    ushort8 pf0 = {0,0,0,0,0,0,0,0}, pf1 = pf0, pf2 = pf0, pf3 = pf0;
    if (0 < kW) { int q = sSh[gid][0]; pf0 = *(const ushort8*)(fbase + (size_t)q * 128); }
    if (1 < kW) { int q = sSh[gid][1]; pf1 = *(const ushort8*)(fbase + (size_t)q * 128); }
    if (2 < kW) { int q = sSh[gid][2]; pf2 = *(const ushort8*)(fbase + (size_t)q * 128); }
    if (3 < kW) { int q = sSh[gid][3]; pf3 = *(const ushort8*)(fbase + (size_t)q * 128); }

    // ---- exp + denominators (registers only) ----
    float den0 = 0.f, den1 = 0.f, den2 = 0.f, den3 = 0.f;
    float4 e0 = {0,0,0,0}, e1 = {0,0,0,0}, e2 = {0,0,0,0}, e3 = {0,0,0,0};
    if (ia < kTot) { e0 = leakyexp4(ad, as0); den0 += e0.x; den1 += e0.y; den2 += e0.z; den3 += e0.w; }
    if (ib < kTot) { e1 = leakyexp4(ad, as1); den0 += e1.x; den1 += e1.y; den2 += e1.z; den3 += e1.w; }
    if (ic < kTot) { e2 = leakyexp4(ad, as2); den0 += e2.x; den1 += e2.y; den2 += e2.z; den3 += e2.w; }
    if (id_ < kTot){ e3 = leakyexp4(ad, as3); den0 += e3.x; den1 += e3.y; den2 += e3.z; den3 += e3.w; }
    for (int i = sub + 64; i < kTot; i += 16) {   // essentially never
        int s = (i < k) ? (int)S.srt[base + i] : d;
        float4 e = leakyexp4(ad, *(const float4*)(S.asrc + (size_t)s * 4));
        den0 += e.x; den1 += e.y; den2 += e.z; den3 += e.w;
    }
#pragma unroll
    for (int off = 1; off <= 8; off <<= 1) {
        den0 += __shfl_xor(den0, off); den1 += __shfl_xor(den1, off);
        den2 += __shfl_xor(den2, off); den3 += __shfl_xor(den3, off);
    }
    float scale = 0.25f * (S.pw ? S.pw[S.pwi] : 1.0f);
    float r0 = scale / (den0 + 1e-16f);
    float r1 = scale / (den1 + 1e-16f);
    float r2 = scale / (den2 + 1e-16f);
    float r3 = scale / (den3 + 1e-16f);

    // ---- weights straight from registers -> LDS ----
    if (ia < kTot)  wSh[gid][ia]  = e0.x * r0 + e0.y * r1 + e0.z * r2 + e0.w * r3;
    if (ib < kTot)  wSh[gid][ib]  = e1.x * r0 + e1.y * r1 + e1.z * r2 + e1.w * r3;
    if (ic < kTot)  wSh[gid][ic]  = e2.x * r0 + e2.y * r1 + e2.z * r2 + e2.w * r3;
    if (id_ < kTot) wSh[gid][id_] = e3.x * r0 + e3.y * r1 + e3.z * r2 + e3.w * r3;
    // producer/consumer in the same wave: in-order LDS pipeline, no barrier

    // ---- gather: lane owns channels sub*8..sub*8+7; 4 rows in flight ----
    float a[8];
#pragma unroll
    for (int i = 0; i < 8; i++) a[i] = 0.f;
    if (0 < kW) { float w = wSh[gid][0];
#pragma unroll
        for (int i = 0; i < 8; i++) a[i] += w * __uint_as_float((unsigned)(unsigned short)pf0[i] << 16); }
    if (1 < kW) { float w = wSh[gid][1];
#pragma unroll
        for (int i = 0; i < 8; i++) a[i] += w * __uint_as_float((unsigned)(unsigned short)pf1[i] << 16); }
    if (2 < kW) { float w = wSh[gid][2];
#pragma unroll
        for (int i = 0; i < 8; i++) a[i] += w * __uint_as_float((unsigned)(unsigned short)pf2[i] << 16); }
    if (3 < kW) { float w = wSh[gid][3];
#pragma unroll
        for (int i = 0; i < 8; i++) a[i] += w * __uint_as_float((unsigned)(unsigned short)pf3[i] << 16); }

    int j = 4;
    for (; j + 4 <= kW; j += 4) {
        float w0 = wSh[gid][j],     w1 = wSh[gid][j + 1];
        float w2 = wSh[gid][j + 2], w3 = wSh[gid][j + 3];
        int t0 = sSh[gid][j],     t1 = sSh[gid][j + 1];
        int t2 = sSh[gid][j + 2], t3 = sSh[gid][j + 3];
        ushort8 va = *(const ushort8*)(fbase + (size_t)t0 * 128);
        ushort8 vb = *(const ushort8*)(fbase + (size_t)t1 * 128);
        ushort8 vc = *(const ushort8*)(fbase + (size_t)t2 * 128);
        ushort8 vd = *(const ushort8*)(fbase + (size_t)t3 * 128);
#pragma unroll
        for (int i = 0; i < 8; i++) {
            a[i] += w0 * __uint_as_float((unsigned)(unsigned short)va[i] << 16);
            a[i] += w1 * __uint_as_float((unsigned)(unsigned short)vb[i] << 16);
            a[i] += w2 * __uint_as_float((unsigned)(unsigned short)vc[i] << 16);
            a[i] += w3 * __uint_as_float((unsigned)(unsigned short)vd[i] << 16);
        }
    }
    for (; j < kW; ++j) {
        float w0 = wSh[gid][j];
        int t0 = sSh[gid][j];
        ushort8 v = *(const ushort8*)(fbase + (size_t)t0 * 128);
#pragma unroll
        for (int i = 0; i < 8; i++)
            a[i] += w0 * __uint_as_float((unsigned)(unsigned short)v[i] << 16);
    }
    for (int jj = CAP; jj < kTot; ++jj) {     // essentially-never fallback
        int s = (jj < k) ? (int)S.srt[base + jj] : d;
        float4 e = leakyexp4(ad, *(const float4*)(S.asrc + (size_t)s * 4));
        float wgt = e.x * r0 + e.y * r1 + e.z * r2 + e.w * r3;
        ushort8 v = *(const ushort8*)(fbase + (size_t)s * 128);
#pragma unroll
        for (int i = 0; i < 8; i++)
            a[i] += wgt * __uint_as_float((unsigned)(unsigned short)v[i] << 16);
    }

    // combine the two segments of this dst (groups g <-> g^1, lanes xor 16)
#pragma unroll
    for (int i = 0; i < 8; i++) a[i] += __shfl_xor(a[i], 16);

    if (seg == 0) {
        size_t idx = (size_t)d * 128 + sub * 8;
        float4* ap = (float4*)(acc + idx);
        float4 lo = make_float4(a[0], a[1], a[2], a[3]);
        float4 hi = make_float4(a[4], a[5], a[6], a[7]);
        if (mode) {
            const float4* b0 = (const float4*)(bias0 + sub * 8);
            const float4* b1 = (const float4*)(bias1 + sub * 8);
            float4 c0 = b0[0], c1 = b0[1], d0v = b1[0], d1v = b1[1];
            ap[0] = make_float4(c0.x + d0v.x + lo.x, c0.y + d0v.y + lo.y,
                                c0.z + d0v.z + lo.z, c0.w + d0v.w + lo.w);
            ap[1] = make_float4(c1.x + d1v.x + hi.x, c1.y + d1v.y + hi.y,
                                c1.z + d1v.z + hi.z, c1.w + d1v.w + hi.w);
        } else {
            float4 rr0 = ap[0], rr1 = ap[1];
            ap[0] = make_float4(rr0.x + lo.x, rr0.y + lo.y, rr0.z + lo.z, rr0.w + lo.w);
            ap[1] = make_float4(rr1.x + hi.x, rr1.y + hi.y, rr1.z + hi.z, rr1.w + hi.w);
        }
    }
}

extern "C" void kernel_launch(void* const* d_in, const int* in_sizes, int n_in,
                              void* d_out, int out_size, void* d_ws, size_t ws_size,
                              hipStream_t stream)
{
    const float* x_var   = (const float*)d_in[0];
    const float* x_cls   = (const float*)d_in[1];
    const int*   mp_var  = (const int*)d_in[2];
    const int*   mp_cls  = (const int*)d_in[3];
    const int*   adj_pos = (const int*)d_in[4];
    const int*   adj_neg = (const int*)d_in[5];
    const float* W_var_emb = (const float*)d_in[6];
    const float* W_cls_emb = (const float*)d_in[7];
    const float* ln_var_g = (const float*)d_in[8];
    const float* ln_var_b = (const float*)d_in[9];
    const float* ln_cls_g = (const float*)d_in[10];
    const float* ln_cls_b = (const float*)d_in[11];
    const float* var_pw = (const float*)d_in[12];
    const float* cls_pw = (const float*)d_in[13];
    const float* sv_W  = (const float*)d_in[14];
    const float* sv_al = (const float*)d_in[15];
    const float* sv_ar = (const float*)d_in[16];
    const float* sv_b  = (const float*)d_in[17];
    const float* sc_W  = (const float*)d_in[18];
    const float* sc_al = (const float*)d_in[19];
    const float* sc_ar = (const float*)d_in[20];
    const float* sc_b  = (const float*)d_in[21];
    const float* cp_Wl = (const float*)d_in[22];
    const float* cp_Wr = (const float*)d_in[23];
    const float* cp_al = (const float*)d_in[24];
    const float* cp_ar = (const float*)d_in[25];
    const float* cp_b  = (const float*)d_in[26];
    const float* cn_Wl = (const float*)d_in[27];
    const float* cn_Wr = (const float*)d_in[28];
    const float* cn_al = (const float*)d_in[29];
    const float* cn_ar = (const float*)d_in[30];
    const float* cn_b  = (const float*)d_in[31];

    float* out0 = (float*)d_out;
    float* out1 = out0 + (size_t)NN * 128;

    float* ws = (float*)d_ws;
    size_t off = 0;
    auto alloc = [&](size_t n) { float* p = ws + off; off += n; return p; };
    float* Wt   = alloc(16384);
    float* Mbuf = alloc(8 * 1024);
    unsigned short* Wbf = (unsigned short*)alloc(8 * 8192);  // 8 x 32KB bf16, fragment order
    float* F   = alloc((size_t)NN * 128);
    float* G   = alloc((size_t)NN * 128);
    float* C   = alloc((size_t)NN * 128);   // hv
    float* D   = alloc((size_t)NN * 128);   // hc
    unsigned short* B1 = (unsigned short*)alloc((size_t)NN * 64);  // bf16 [NN][128]
    unsigned short* B2 = (unsigned short*)alloc((size_t)NN * 64);
    unsigned short* Pc = (unsigned short*)alloc((size_t)NN * 64);
    unsigned short* Pd = (unsigned short*)alloc((size_t)NN * 64);
    float* dl   = alloc(NN * 4);
    float* dr   = alloc(NN * 4);
    float* dl2  = alloc(NN * 4);
    float* dr2  = alloc(NN * 4);
    float* dl3  = alloc(NN * 4);
    float* dr3  = alloc(NN * 4);
    float* dl4  = alloc(NN * 4);
    float* dr4  = alloc(NN * 4);
    int* counts8 = (int*)alloc(8 * NN);
    int* starts8 = (int*)alloc(8 * NN);
    int* bcnt    = (int*)alloc(8 * NBKT);
    int* bstart  = (int*)alloc(8 * (NBKT + 1));
    int* bcur    = (int*)alloc(8 * NBKT);
    unsigned* recs = (unsigned*)alloc((size_t)8 * EE);
    unsigned short* sortedU = (unsigned short*)alloc((size_t)4 * EE);

    const float* WtEv = Wt;
    const float* WtEc = Wt + 8192;

    Ptr8 srcP, dstP;
    srcP.p[0] = mp_var;            dstP.p[0] = mp_var + EE;
    srcP.p[1] = mp_var + 2 * EE;   dstP.p[1] = mp_var + 3 * EE;
    srcP.p[2] = mp_cls;            dstP.p[2] = mp_cls + EE;
    srcP.p[3] = mp_cls + 2 * EE;   dstP.p[3] = mp_cls + 3 * EE;
    srcP.p[4] = adj_pos;           dstP.p[4] = adj_pos + EE;
    srcP.p[5] = adj_pos + EE;      dstP.p[5] = adj_pos;
    srcP.p[6] = adj_neg;           dstP.p[6] = adj_neg + EE;
    srcP.p[7] = adj_neg + EE;      dstP.p[7] = adj_neg;

    MArgs ma;
    ma.w[0] = sv_W;           ma.al[0] = sv_al;        ma.ar[0] = sv_ar;
    ma.w[1] = sv_W + 16384;   ma.al[1] = sv_al + 512;  ma.ar[1] = sv_ar + 512;
    ma.w[2] = sc_W;           ma.al[2] = sc_al;        ma.ar[2] = sc_ar;
    ma.w[3] = sc_W + 16384;   ma.al[3] = sc_al + 512;  ma.ar[3] = sc_ar + 512;
    ma.w[4] = cp_Wl;          ma.al[4] = cp_al;        ma.ar[4] = cp_ar;
    ma.w[5] = cp_Wr;          ma.al[5] = cp_al;        ma.ar[5] = cp_ar;
    ma.w[6] = cn_Wl;          ma.al[6] = cn_al;        ma.ar[6] = cn_ar;
    ma.w[7] = cn_Wr;          ma.al[7] = cn_al;        ma.ar[7] = cn_ar;

    const int PB = (NN + 31) / 32;   // 1563 blocks, 32 rows each
    const int AB = NN / 8;           // 6250 chunks of 8 dsts per pair-set
    const int NBE = NN / 16;         // 3125 embed blocks per side (16 rows each)

    // ---- prep (Wt needed by embed in the next launch) ----
    hipMemsetAsync(bcnt, 0, 8 * NBKT * sizeof(int), stream);
    prep_all<<<136, 256, 0, stream>>>(W_var_emb, W_cls_emb, Wt, ma, Mbuf, Wbf);

    // ---- embed (both sides) || bucket_count in one launch ----
    EmbArgs Ev = { x_var, WtEv, ln_var_g, ln_var_b, var_pw, sv_b, F, C };
    EmbArgs Ec = { x_cls, WtEc, ln_cls_g, ln_cls_b, cls_pw, sc_b, G, D };
    fused_embed_count<<<2 * NBE + 8 * PA_B, 256, 0, stream>>>(Ev, Ec, NBE, dstP, bcnt);

    bucket_scan<<<8, 256, 0, stream>>>(bcnt, bstart, bcur);

    // ---- self projections (both sides, 2 pairs) || bucket_place ----
    ProjArgs Ps0 = { C, Wbf + 0 * 16384, Wbf + 1 * 16384, Mbuf + 0 * 1024, Mbuf + 1 * 1024,
                     B1, B2, (float4*)dl, (float4*)dr, (float4*)dl2, (float4*)dr2 };
    ProjArgs Ps1 = { D, Wbf + 2 * 16384, Wbf + 3 * 16384, Mbuf + 2 * 1024, Mbuf + 3 * 1024,
                     Pc, Pd, (float4*)dl3, (float4*)dr3, (float4*)dl4, (float4*)dr4 };
    fused_proj_place<<<2 * PB + 8 * PA_B, 256, 0, stream>>>(Ps0, Ps1, PB,
                                                            srcP, dstP, bcur, recs);

    bucket_final<<<8 * NBKT, 256, 0, stream>>>(recs, bstart, starts8, counts8, sortedU);

    // ---- self aggregation: both sides in one launch ----
    {
        SegArg VA, VB, CA, CB;
        VA.starts = starts8 + 0 * NN; VA.counts = counts8 + 0 * NN;
        VA.srt = sortedU + (size_t)0 * EE;
        VA.adst = dl;  VA.asrc = dr;  VA.feats = B1; VA.pw = var_pw; VA.pwi = 0; VA.hasLoop = 1;
        VB.starts = starts8 + 1 * NN; VB.counts = counts8 + 1 * NN;
        VB.srt = sortedU + (size_t)1 * EE;
        VB.adst = dl2; VB.asrc = dr2; VB.feats = B2; VB.pw = var_pw; VB.pwi = 1; VB.hasLoop = 1;
        CA.starts = starts8 + 2 * NN; CA.counts = counts8 + 2 * NN;
        CA.srt = sortedU + (size_t)2 * EE;
        CA.adst = dl3; CA.asrc = dr3; CA.feats = Pc; CA.pw = cls_pw; CA.pwi = 0; CA.hasLoop = 1;
        CB.starts = starts8 + 3 * NN; CB.counts = counts8 + 3 * NN;
        CB.srt = sortedU + (size_t)3 * EE;
        CB.adst = dl4; CB.asrc = dr4; CB.feats = Pd; CB.pw = cls_pw; CB.pwi = 1; CB.hasLoop = 1;
        agg_fused2<<<2 * AB, 256, 0, stream>>>(VA, VB, F, CA, CB, G, cp_b, cn_b, AB, 0);
    }

    // ---- cross attention: both projections in one launch ----
    ProjArgs Pc0 = { F, Wbf + 4 * 16384, Wbf + 6 * 16384, Mbuf + 4 * 1024, Mbuf + 6 * 1024,
                     B1, Pc, (float4*)dl, (float4*)dr, (float4*)dl3, (float4*)dr3 };
    ProjArgs Pc1 = { G, Wbf + 5 * 16384, Wbf + 7 * 16384, Mbuf + 5 * 1024, Mbuf + 7 * 1024,
                     B2, Pd, (float4*)dl2, (float4*)dr2, (float4*)dl4, (float4*)dr4 };
    mfma_proj2<<<2 * PB, 256, 0, stream>>>(Pc0, Pc1, PB);

    // ---- cross aggregation: both outputs in one launch ----
    {
        SegArg OA, OB, PA, PBs;
        OA.starts = starts8 + 4 * NN; OA.counts = counts8 + 4 * NN;
        OA.srt = sortedU + (size_t)4 * EE;
        OA.adst = dl;  OA.asrc = dr2; OA.feats = B2; OA.pw = nullptr; OA.pwi = 0; OA.hasLoop = 0;
        OB.starts = starts8 + 6 * NN; OB.counts = counts8 + 6 * NN;
        OB.srt = sortedU + (size_t)6 * EE;
        OB.adst = dl3; OB.asrc = dr4; OB.feats = Pd; OB.pw = nullptr; OB.pwi = 0; OB.hasLoop = 0;
        PA.starts = starts8 + 5 * NN; PA.counts = counts8 + 5 * NN;
        PA.srt = sortedU + (size_t)5 * EE;
        PA.adst = dl2; PA.asrc = dr;  PA.feats = B1; PA.pw = nullptr; PA.pwi = 0; PA.hasLoop = 0;
        PBs.starts = starts8 + 7 * NN; PBs.counts = counts8 + 7 * NN;
        PBs.srt = sortedU + (size_t)7 * EE;
        PBs.adst = dl4; PBs.asrc = dr3; PBs.feats = Pc; PBs.pw = nullptr; PBs.pwi = 0; PBs.hasLoop = 0;
        agg_fused2<<<2 * AB, 256, 0, stream>>>(OA, OB, out0, PA, PBs, out1, cp_b, cn_b, AB, 1);
    }
}

// Round 10
// 648.614 us; speedup vs baseline: 1.1152x; 1.1152x over previous
//
#include <hip/hip_runtime.h>
#include <hip/hip_bf16.h>

#define NN 50000
#define EE 640000
#define NEG 0.2f
#define CAP 64           // per-segment cache; degree ~ Poisson(12.8), P(k>=64) ~ 1e-24

#define BSH 9                          // 512 dsts per bucket
#define NBKT 98                        // ceil(NN/512)
#define FCAP 7168                      // LDS record stage in bucket_final
#define CHUNKA 8192
#define PA_B 79                        // ceil(EE/CHUNKA)

struct Ptr8 { const int* p[8]; };
struct MArgs { const float* w[8]; const float* al[8]; const float* ar[8]; };

struct SegArg {
    const int* starts;
    const int* counts;
    const unsigned short* srt;
    const float* adst;
    const float* asrc;
    const unsigned short* feats;
    const float* pw;
    int pwi;
    int hasLoop;
};

struct ProjArgs {
    const float* in;
    const unsigned short* Wp0; const unsigned short* Wp1;
    const float* M0; const float* M1;
    unsigned short* ob0; unsigned short* ob1;
    float4* dl0; float4* dr0; float4* dl1; float4* dr1;
};

struct EmbArgs {
    const float* x; const float* Wt; const float* g; const float* b;
    const float* pw; const float* sb; float* F; float* C;
};

typedef __attribute__((ext_vector_type(8))) short short8;
typedef __attribute__((ext_vector_type(8))) unsigned short ushort8;
typedef __attribute__((ext_vector_type(4))) float floatx4;

__device__ __forceinline__ unsigned short f2bf(float x) {
    unsigned b = __float_as_uint(x);
    b = b + 0x7fffu + ((b >> 16) & 1u);   // RNE
    return (unsigned short)(b >> 16);
}

__device__ __forceinline__ float4 leakyexp4(float4 ad, float4 as) {
    float v0 = ad.x + as.x, v1 = ad.y + as.y, v2 = ad.z + as.z, v3 = ad.w + as.w;
    v0 = v0 > 0.f ? v0 : NEG * v0;
    v1 = v1 > 0.f ? v1 : NEG * v1;
    v2 = v2 > 0.f ? v2 : NEG * v2;
    v3 = v3 > 0.f ? v3 : NEG * v3;
    return make_float4(__expf(v0), __expf(v1), __expf(v2), __expf(v3));
}

// ---------------- merged one-shot prep: transpose emb W + make M + fragment-order W ----
__global__ void prep_all(const float* __restrict__ wev, const float* __restrict__ wec,
                         float* __restrict__ Wt, MArgs a, float* __restrict__ Mbuf,
                         unsigned short* __restrict__ Wbf)
{
    int b = blockIdx.x;
    if (b < 64) {
        int i = b * 256 + threadIdx.x;
        if (i < 8192) { Wt[i] = wev[(i & 127) * 64 + (i >> 7)]; }
        else { int j = i - 8192; Wt[i] = wec[(j & 127) * 64 + (j >> 7)]; }
        return;
    }
    if (b < 128) {
        int tid = (b - 64) * 256 + threadIdx.x;   // 0..16383
        int w = tid >> 11;
        int idx = tid & 2047;
        int tile = idx >> 6;          // ct*4 + kc
        int lane = idx & 63;
        int ct = tile >> 2, kc = tile & 3;
        int n = ct * 16 + (lane & 15);
        int k0 = kc * 32 + (lane >> 4) * 8;
        const float* src = a.w[w] + n * 128 + k0;
        short8 v;
#pragma unroll
        for (int j = 0; j < 8; j++) v[j] = (short)f2bf(src[j]);
        *(short8*)&Wbf[(size_t)tid * 8] = v;
        return;
    }
    {   // make_M: M[p] = W_p^T @ [attL | attR]
        int w = b - 128;
        const float* W  = a.w[w];
        const float* AL = a.al[w];
        const float* AR = a.ar[w];
        for (int e = threadIdx.x; e < 1024; e += 256) {
            int k = e >> 3, h = e & 7;
            const float* att = (h < 4) ? AL : AR;
            int hh = h & 3;
            float s = 0.f;
            for (int c = 0; c < 128; c++) s += W[c * 128 + k] * att[c * 4 + hh];
            Mbuf[w * 1024 + e] = s;
        }
    }
}

// ---------------- embedding GEMM + LayerNorm (both sides in one launch) ----------------
__global__ void embed_ln2(EmbArgs Ea, EmbArgs Eb, int nb)
{
    __shared__ float lx[8][64];
    __shared__ float red[2][8][2];
    int half = blockIdx.x >= nb;
    const EmbArgs E = half ? Eb : Ea;
    int blk = blockIdx.x - (half ? nb : 0);
    int c = threadIdx.x;
    int n0 = blk * 8;
    for (int t = c; t < 8 * 64; t += 128) {
        lx[t >> 6][t & 63] = E.x[(size_t)(n0 + (t >> 6)) * 64 + (t & 63)];
    }
    __syncthreads();
    float acc[8];
#pragma unroll
    for (int m = 0; m < 8; m++) acc[m] = 0.f;
    for (int k = 0; k < 64; k++) {
        float w = E.Wt[k * 128 + c];
#pragma unroll
        for (int m = 0; m < 8; m++) acc[m] += lx[m][k] * w;
    }
    int lane = c & 63, wv = c >> 6;
#pragma unroll
    for (int m = 0; m < 8; m++) {
        float s1 = acc[m], s2 = acc[m] * acc[m];
        for (int off = 32; off; off >>= 1) { s1 += __shfl_xor(s1, off); s2 += __shfl_xor(s2, off); }
        if (lane == 0) { red[wv][m][0] = s1; red[wv][m][1] = s2; }
    }
    __syncthreads();
    float biassum = E.pw[0] * E.sb[c] + E.pw[1] * E.sb[128 + c];
    float gg = E.g[c], bb = E.b[c];
#pragma unroll
    for (int m = 0; m < 8; m++) {
        float s1 = red[0][m][0] + red[1][m][0];
        float s2 = red[0][m][1] + red[1][m][1];
        float mu  = s1 * (1.f / 128.f);
        float var = s2 * (1.f / 128.f) - mu * mu;
        float inv = rsqrtf(var + 1e-5f);
        float v = acc[m];
        size_t idx = (size_t)(n0 + m) * 128 + c;
        E.F[idx] = v + biassum;
        E.C[idx] = (v - mu) * inv * gg + bb;
    }
}

// ---------------- fused pair projection, wave-per-(rowgroup x colhalf) ----------------
__global__ __launch_bounds__(256) void mfma_proj2(ProjArgs Pa, ProjArgs Pb, int nb)
{
    __shared__ float ML[2048];            // 2 x 128 x 8

    int half = blockIdx.x >= nb;
    const ProjArgs P = half ? Pb : Pa;
    int blk = blockIdx.x - (half ? nb : 0);

    int t = threadIdx.x;
    for (int i = t; i < 2048; i += 256) ML[i] = (i < 1024) ? P.M0[i] : P.M1[i - 1024];
    __syncthreads();

    int w = t >> 6, lane = t & 63;
    int rg = w & 1, chh = w >> 1;
    int ln = lane & 15, quad = lane >> 4;
    int rbase = blk * 32 + rg * 16;
    int row = rbase + ln;
    int arow = (row < NN) ? row : (NN - 1);
    const float* MLh = &ML[chh * 1024];

    short8 afrag[4];
    float p[8];
#pragma unroll
    for (int h = 0; h < 8; h++) p[h] = 0.f;
#pragma unroll
    for (int kc = 0; kc < 4; kc++) {
        int k0 = kc * 32 + quad * 8;
        const float* ap = P.in + (size_t)arow * 128 + k0;
        float av[8];
#pragma unroll
        for (int j = 0; j < 8; j++) av[j] = ap[j];
#pragma unroll
        for (int j = 0; j < 8; j++) {
            afrag[kc][j] = (short)f2bf(av[j]);
            const float* mrow = &MLh[(k0 + j) * 8];
#pragma unroll
            for (int h = 0; h < 8; h++) p[h] += av[j] * mrow[h];
        }
    }
#pragma unroll
    for (int h = 0; h < 8; h++) {
        p[h] += __shfl_xor(p[h], 16);
        p[h] += __shfl_xor(p[h], 32);
    }
    if (quad == 0 && row < NN) {
        if (chh == 0) {
            P.dl0[row] = make_float4(p[0], p[1], p[2], p[3]);
            P.dr0[row] = make_float4(p[4], p[5], p[6], p[7]);
        } else {
            P.dl1[row] = make_float4(p[0], p[1], p[2], p[3]);
            P.dr1[row] = make_float4(p[4], p[5], p[6], p[7]);
        }
    }

    // ---- phase 0: MFMA with Wp0 (this wave's 4 ct tiles) ----
#pragma unroll
    for (int cti = 0; cti < 4; cti++) {
        int ct = chh * 4 + cti;
        floatx4 acc = {0.f, 0.f, 0.f, 0.f};
#pragma unroll
        for (int kc = 0; kc < 4; kc++) {
            short8 bfr = *(const short8*)&P.Wp0[(size_t)((ct * 4 + kc) * 64 + lane) * 8];
            acc = __builtin_amdgcn_mfma_f32_16x16x32_bf16(afrag[kc], bfr, acc, 0, 0, 0);
        }
#pragma unroll
        for (int r = 0; r < 4; r++) {
            int rr = rbase + quad * 4 + r;
            if (rr < NN) P.ob0[(size_t)rr * 128 + ct * 16 + ln] = f2bf(acc[r]);
        }
    }
    // ---- phase 1: MFMA with Wp1 ----
#pragma unroll
    for (int cti = 0; cti < 4; cti++) {
        int ct = chh * 4 + cti;
        floatx4 acc = {0.f, 0.f, 0.f, 0.f};
#pragma unroll
        for (int kc = 0; kc < 4; kc++) {
            short8 bfr = *(const short8*)&P.Wp1[(size_t)((ct * 4 + kc) * 64 + lane) * 8];
            acc = __builtin_amdgcn_mfma_f32_16x16x32_bf16(afrag[kc], bfr, acc, 0, 0, 0);
        }
#pragma unroll
        for (int r = 0; r < 4; r++) {
            int rr = rbase + quad * 4 + r;
            if (rr < NN) P.ob1[(size_t)rr * 128 + ct * 16 + ln] = f2bf(acc[r]);
        }
    }
}

// ================= two-level bucket sort (8 edge lists) =================
__global__ void bucket_count(Ptr8 dst, int* __restrict__ bcnt)
{
    __shared__ int h[NBKT];
    int l = blockIdx.x / PA_B, cb = blockIdx.x % PA_B;
    const int* dp = dst.p[l];
    for (int i = threadIdx.x; i < NBKT; i += 256) h[i] = 0;
    __syncthreads();
    int e0 = cb * CHUNKA;
    for (int i = threadIdx.x; i < CHUNKA; i += 256) {
        int e = e0 + i;
        if (e < EE) atomicAdd(&h[dp[e] >> BSH], 1);
    }
    __syncthreads();
    for (int i = threadIdx.x; i < NBKT; i += 256)
        if (h[i]) atomicAdd(&bcnt[l * NBKT + i], h[i]);
}

__global__ void bucket_scan(const int* __restrict__ bcnt, int* __restrict__ bstart,
                            int* __restrict__ bcur)
{
    __shared__ int sh[NBKT];
    int l = blockIdx.x;
    for (int i = threadIdx.x; i < NBKT; i += 256) sh[i] = bcnt[l * NBKT + i];
    __syncthreads();
    if (threadIdx.x == 0) {
        int acc = 0;
        for (int i = 0; i < NBKT; i++) { int t = sh[i]; sh[i] = acc; acc += t; }
    }
    __syncthreads();
    for (int i = threadIdx.x; i < NBKT; i += 256) {
        bstart[l * (NBKT + 1) + i] = sh[i];
        bcur[l * NBKT + i] = sh[i];
    }
    if (threadIdx.x == 0) bstart[l * (NBKT + 1) + NBKT] = EE;
}

__global__ void bucket_place(Ptr8 src, Ptr8 dst, int* __restrict__ bcur,
                             unsigned* __restrict__ recs)
{
    __shared__ int h[NBKT];
    __shared__ int base[NBKT];
    int l = blockIdx.x / PA_B, cb = blockIdx.x % PA_B;
    const int* sp = src.p[l];
    const int* dp = dst.p[l];
    for (int i = threadIdx.x; i < NBKT; i += 256) h[i] = 0;
    __syncthreads();
    int e0 = cb * CHUNKA;
    for (int i = threadIdx.x; i < CHUNKA; i += 256) {
        int e = e0 + i;
        if (e < EE) atomicAdd(&h[dp[e] >> BSH], 1);
    }
    __syncthreads();
    for (int i = threadIdx.x; i < NBKT; i += 256) {
        int c = h[i];
        base[i] = c ? atomicAdd(&bcur[l * NBKT + i], c) : 0;
        h[i] = 0;
    }
    __syncthreads();
    unsigned* rl = recs + (size_t)l * EE;
    for (int i = threadIdx.x; i < CHUNKA; i += 256) {
        int e = e0 + i;
        if (e >= EE) continue;
        int d = dp[e];
        int b = d >> BSH;
        int pos = base[b] + atomicAdd(&h[b], 1);
        rl[pos] = ((unsigned)sp[e] << 16) | (unsigned)d;
    }
}

// one block per 512-dst bucket: stage recs in LDS, parallel scan, exact placement
__global__ __launch_bounds__(256) void bucket_final(
    const unsigned* __restrict__ recs, const int* __restrict__ bstart,
    int* __restrict__ starts8, int* __restrict__ counts8,
    unsigned short* __restrict__ sortedU)
{
    __shared__ unsigned R[FCAP];
    __shared__ int cnt[512];
    __shared__ int cur[512];
    __shared__ int psum[256];
    int l = blockIdx.x / NBKT, b = blockIdx.x % NBKT;
    int d0 = b << BSH;
    int nd = min(512, NN - d0);
    int ebase = bstart[l * (NBKT + 1) + b];
    int ecnt  = bstart[l * (NBKT + 1) + b + 1] - ebase;
    const unsigned* rp = recs + (size_t)l * EE + ebase;
    int t = threadIdx.x;
    bool inLds = (ecnt <= FCAP);

    for (int i = t; i < 512; i += 256) cnt[i] = 0;
    __syncthreads();
    for (int i = t; i < ecnt; i += 256) {
        unsigned r = rp[i];
        if (inLds) R[i] = r;
        atomicAdd(&cnt[(r & 0xffffu) - d0], 1);
    }
    __syncthreads();
    // exclusive scan of cnt[512]: pairwise partials + 256-ladder
    int s0 = cnt[2 * t] + cnt[2 * t + 1];
    psum[t] = s0;
    __syncthreads();
    for (int off = 1; off < 256; off <<= 1) {
        int x = (t >= off) ? psum[t - off] : 0;
        __syncthreads();
        psum[t] += x;
        __syncthreads();
    }
    int excl = psum[t] - s0;
    cur[2 * t] = excl;
    cur[2 * t + 1] = excl + cnt[2 * t];
    __syncthreads();
    for (int i = t; i < nd; i += 256) {
        starts8[l * NN + d0 + i] = ebase + cur[i];
        counts8[l * NN + d0 + i] = cnt[i];
    }
    __syncthreads();
    unsigned short* so = sortedU + (size_t)l * EE + ebase;
    for (int i = t; i < ecnt; i += 256) {
        unsigned r = inLds ? R[i] : rp[i];
        int dloc = (int)(r & 0xffffu) - d0;
        int pos = atomicAdd(&cur[dloc], 1);
        so[pos] = (unsigned short)(r >> 16);
    }
}

// ---------------- fused pair aggregation: 16-lane groups, reg-held exp ----
// R8 structure + software-pipelined gather: two 4-row batches rotate so
// batch n+1's loads are in flight while batch n's FMAs execute -- halves
// the exposed HBM/L2 round-trips per group. All loads guarded (idx < kW).
__global__ __launch_bounds__(256, 4) void agg_fused2(
    SegArg A0, SegArg B0, float* __restrict__ acc0,
    SegArg A1, SegArg B1, float* __restrict__ acc1,
    const float* __restrict__ bias0, const float* __restrict__ bias1,
    int nb, int mode)
{
    __shared__ float          wSh[16][CAP + 1];   // stride 65 words (bank-padded)
    __shared__ unsigned short sSh[16][CAP + 2];   // stride 33 words

    int t = threadIdx.x;
    int gid = t >> 4, sub = t & 15;
    int seg = gid & 1;
    int half = blockIdx.x >= nb;
    int blk = blockIdx.x - (half ? nb : 0);
    int d = blk * 8 + (gid >> 1);

    const SegArg S = half ? (seg ? B1 : A1) : (seg ? B0 : A0);
    float* acc = half ? acc1 : acc0;

    int base = S.starts[d];
    int k = S.counts[d];
    int kTot = k + S.hasLoop;
    int kW = kTot < CAP ? kTot : CAP;

    float4 ad = *(const float4*)(S.adst + (size_t)d * 4);

    // ---- pass 1a: src ids -> LDS immediately ----
    int ia = sub, ib = sub + 16, ic = sub + 32, id_ = sub + 48;
    int s0 = d, s1 = d, s2 = d, s3 = d;
    if (ia < kTot) { if (ia < k) s0 = (int)S.srt[base + ia]; sSh[gid][ia] = (unsigned short)s0; }
    if (ib < kTot) { if (ib < k) s1 = (int)S.srt[base + ib]; sSh[gid][ib] = (unsigned short)s1; }
    if (ic < kTot) { if (ic < k) s2 = (int)S.srt[base + ic]; sSh[gid][ic] = (unsigned short)s2; }
    if (id_ < kTot){ if (id_ < k) s3 = (int)S.srt[base + id_]; sSh[gid][id_] = (unsigned short)s3; }

    // ---- pass 1b: issue asrc loads ----
    float4 as0 = {0,0,0,0}, as1 = {0,0,0,0}, as2 = {0,0,0,0}, as3 = {0,0,0,0};
    if (ia < kTot)  as0 = *(const float4*)(S.asrc + (size_t)s0 * 4);
    if (ib < kTot)  as1 = *(const float4*)(S.asrc + (size_t)s1 * 4);
    if (ic < kTot)  as2 = *(const float4*)(S.asrc + (size_t)s2 * 4);
    if (id_ < kTot) as3 = *(const float4*)(S.asrc + (size_t)s3 * 4);

    // ---- prefetch first 4 gather rows (independent of softmax) ----
    const unsigned short* fbase = S.feats + sub * 8;
    ushort8 c0 = {0,0,0,0,0,0,0,0}, c1 = c0, c2 = c0, c3 = c0;
    if (0 < kW) { int q = sSh[gid][0]; c0 = *(const ushort8*)(fbase + (size_t)q * 128); }
    if (1 < kW) { int q = sSh[gid][1]; c1 = *(const ushort8*)(fbase + (size_t)q * 128); }
    if (2 < kW) { int q = sSh[gid][2]; c2 = *(const ushort8*)(fbase + (size_t)q * 128); }
    if (3 < kW) { int q = sSh[gid][3]; c3 = *(const ushort8*)(fbase + (size_t)q * 128); }

    // ---- exp + denominators (registers only) ----
    float den0 = 0.f, den1 = 0.f, den2 = 0.f, den3 = 0.f;
    float4 e0 = {0,0,0,0}, e1 = {0,0,0,0}, e2 = {0,0,0,0}, e3 = {0,0,0,0};
    if (ia < kTot) { e0 = leakyexp4(ad, as0); den0 += e0.x; den1 += e0.y; den2 += e0.z; den3 += e0.w; }
    if (ib < kTot) { e1 = leakyexp4(ad, as1); den0 += e1.x; den1 += e1.y; den2 += e1.z; den3 += e1.w; }
    if (ic < kTot) { e2 = leakyexp4(ad, as2); den0 += e2.x; den1 += e2.y; den2 += e2.z; den3 += e2.w; }
    if (id_ < kTot){ e3 = leakyexp4(ad, as3); den0 += e3.x; den1 += e3.y; den2 += e3.z; den3 += e3.w; }
    for (int i = sub + 64; i < kTot; i += 16) {   // essentially never
        int s = (i < k) ? (int)S.srt[base + i] : d;
        float4 e = leakyexp4(ad, *(const float4*)(S.asrc + (size_t)s * 4));
        den0 += e.x; den1 += e.y; den2 += e.z; den3 += e.w;
    }
#pragma unroll
    for (int off = 1; off <= 8; off <<= 1) {
        den0 += __shfl_xor(den0, off); den1 += __shfl_xor(den1, off);
        den2 += __shfl_xor(den2, off); den3 += __shfl_xor(den3, off);
    }
    float scale = 0.25f * (S.pw ? S.pw[S.pwi] : 1.0f);
    float r0 = scale / (den0 + 1e-16f);
    float r1 = scale / (den1 + 1e-16f);
    float r2 = scale / (den2 + 1e-16f);
    float r3 = scale / (den3 + 1e-16f);

    // ---- weights straight from registers -> LDS ----
    if (ia < kTot)  wSh[gid][ia]  = e0.x * r0 + e0.y * r1 + e0.z * r2 + e0.w * r3;
    if (ib < kTot)  wSh[gid][ib]  = e1.x * r0 + e1.y * r1 + e1.z * r2 + e1.w * r3;
    if (ic < kTot)  wSh[gid][ic]  = e2.x * r0 + e2.y * r1 + e2.z * r2 + e2.w * r3;
    if (id_ < kTot) wSh[gid][id_] = e3.x * r0 + e3.y * r1 + e3.z * r2 + e3.w * r3;
    // producer/consumer in the same wave: in-order LDS pipeline, no barrier

    // ---- gather: rotated double-batch (batch n+1 loads in flight during
    //      batch n's FMAs); lane owns channels sub*8..sub*8+7 ----
    float a[8];
#pragma unroll
    for (int i = 0; i < 8; i++) a[i] = 0.f;
    int j = 0;
    for (;;) {
        int nj = j + 4;
        ushort8 n0 = {0,0,0,0,0,0,0,0}, n1 = n0, n2 = n0, n3 = n0;
        if (nj     < kW) { int q = sSh[gid][nj];     n0 = *(const ushort8*)(fbase + (size_t)q * 128); }
        if (nj + 1 < kW) { int q = sSh[gid][nj + 1]; n1 = *(const ushort8*)(fbase + (size_t)q * 128); }
        if (nj + 2 < kW) { int q = sSh[gid][nj + 2]; n2 = *(const ushort8*)(fbase + (size_t)q * 128); }
        if (nj + 3 < kW) { int q = sSh[gid][nj + 3]; n3 = *(const ushort8*)(fbase + (size_t)q * 128); }
        if (j     < kW) { float w = wSh[gid][j];
#pragma unroll
            for (int i = 0; i < 8; i++) a[i] += w * __uint_as_float((unsigned)(unsigned short)c0[i] << 16); }
        if (j + 1 < kW) { float w = wSh[gid][j + 1];
#pragma unroll
            for (int i = 0; i < 8; i++) a[i] += w * __uint_as_float((unsigned)(unsigned short)c1[i] << 16); }
        if (j + 2 < kW) { float w = wSh[gid][j + 2];
#pragma unroll
            for (int i = 0; i < 8; i++) a[i] += w * __uint_as_float((unsigned)(unsigned short)c2[i] << 16); }
        if (j + 3 < kW) { float w = wSh[gid][j + 3];
#pragma unroll
            for (int i = 0; i < 8; i++) a[i] += w * __uint_as_float((unsigned)(unsigned short)c3[i] << 16); }
        if (nj >= kW) break;
        c0 = n0; c1 = n1; c2 = n2; c3 = n3;
        j = nj;
    }
    for (int jj = CAP; jj < kTot; ++jj) {     // essentially-never fallback
        int s = (jj < k) ? (int)S.srt[base + jj] : d;
        float4 e = leakyexp4(ad, *(const float4*)(S.asrc + (size_t)s * 4));
        float wgt = e.x * r0 + e.y * r1 + e.z * r2 + e.w * r3;
        ushort8 v = *(const ushort8*)(fbase + (size_t)s * 128);
#pragma unroll
        for (int i = 0; i < 8; i++)
            a[i] += wgt * __uint_as_float((unsigned)(unsigned short)v[i] << 16);
    }

    // combine the two segments of this dst (groups g <-> g^1, lanes xor 16)
#pragma unroll
    for (int i = 0; i < 8; i++) a[i] += __shfl_xor(a[i], 16);

    if (seg == 0) {
        size_t idx = (size_t)d * 128 + sub * 8;
        float4* ap = (float4*)(acc + idx);
        float4 lo = make_float4(a[0], a[1], a[2], a[3]);
        float4 hi = make_float4(a[4], a[5], a[6], a[7]);
        if (mode) {
            const float4* b0 = (const float4*)(bias0 + sub * 8);
            const float4* b1 = (const float4*)(bias1 + sub * 8);
            float4 c0b = b0[0], c1b = b0[1], d0v = b1[0], d1v = b1[1];
            ap[0] = make_float4(c0b.x + d0v.x + lo.x, c0b.y + d0v.y + lo.y,
                                c0b.z + d0v.z + lo.z, c0b.w + d0v.w + lo.w);
            ap[1] = make_float4(c1b.x + d1v.x + hi.x, c1b.y + d1v.y + hi.y,
                                c1b.z + d1v.z + hi.z, c1b.w + d1v.w + hi.w);
        } else {
            float4 rr0 = ap[0], rr1 = ap[1];
            ap[0] = make_float4(rr0.x + lo.x, rr0.y + lo.y, rr0.z + lo.z, rr0.w + lo.w);
            ap[1] = make_float4(rr1.x + hi.x, rr1.y + hi.y, rr1.z + hi.z, rr1.w + hi.w);
        }
    }
}

extern "C" void kernel_launch(void* const* d_in, const int* in_sizes, int n_in,
                              void* d_out, int out_size, void* d_ws, size_t ws_size,
                              hipStream_t stream)
{
    const float* x_var   = (const float*)d_in[0];
    const float* x_cls   = (const float*)d_in[1];
    const int*   mp_var  = (const int*)d_in[2];
    const int*   mp_cls  = (const int*)d_in[3];
    const int*   adj_pos = (const int*)d_in[4];
    const int*   adj_neg = (const int*)d_in[5];
    const float* W_var_emb = (const float*)d_in[6];
    const float* W_cls_emb = (const float*)d_in[7];
    const float* ln_var_g = (const float*)d_in[8];
    const float* ln_var_b = (const float*)d_in[9];
    const float* ln_cls_g = (const float*)d_in[10];
    const float* ln_cls_b = (const float*)d_in[11];
    const float* var_pw = (const float*)d_in[12];
    const float* cls_pw = (const float*)d_in[13];
    const float* sv_W  = (const float*)d_in[14];
    const float* sv_al = (const float*)d_in[15];
    const float* sv_ar = (const float*)d_in[16];
    const float* sv_b  = (const float*)d_in[17];
    const float* sc_W  = (const float*)d_in[18];
    const float* sc_al = (const float*)d_in[19];
    const float* sc_ar = (const float*)d_in[20];
    const float* sc_b  = (const float*)d_in[21];
    const float* cp_Wl = (const float*)d_in[22];
    const float* cp_Wr = (const float*)d_in[23];
    const float* cp_al = (const float*)d_in[24];
    const float* cp_ar = (const float*)d_in[25];
    const float* cp_b  = (const float*)d_in[26];
    const float* cn_Wl = (const float*)d_in[27];
    const float* cn_Wr = (const float*)d_in[28];
    const float* cn_al = (const float*)d_in[29];
    const float* cn_ar = (const float*)d_in[30];
    const float* cn_b  = (const float*)d_in[31];

    float* out0 = (float*)d_out;
    float* out1 = out0 + (size_t)NN * 128;

    float* ws = (float*)d_ws;
    size_t off = 0;
    auto alloc = [&](size_t n) { float* p = ws + off; off += n; return p; };
    float* Wt   = alloc(16384);
    float* Mbuf = alloc(8 * 1024);
    unsigned short* Wbf = (unsigned short*)alloc(8 * 8192);  // 8 x 32KB bf16, fragment order
    float* F   = alloc((size_t)NN * 128);
    float* G   = alloc((size_t)NN * 128);
    float* C   = alloc((size_t)NN * 128);   // hv
    float* D   = alloc((size_t)NN * 128);   // hc
    unsigned short* B1 = (unsigned short*)alloc((size_t)NN * 64);  // bf16 [NN][128]
    unsigned short* B2 = (unsigned short*)alloc((size_t)NN * 64);
    unsigned short* Pc = (unsigned short*)alloc((size_t)NN * 64);
    unsigned short* Pd = (unsigned short*)alloc((size_t)NN * 64);
    float* dl   = alloc(NN * 4);
    float* dr   = alloc(NN * 4);
    float* dl2  = alloc(NN * 4);
    float* dr2  = alloc(NN * 4);
    float* dl3  = alloc(NN * 4);
    float* dr3  = alloc(NN * 4);
    float* dl4  = alloc(NN * 4);
    float* dr4  = alloc(NN * 4);
    int* counts8 = (int*)alloc(8 * NN);
    int* starts8 = (int*)alloc(8 * NN);
    int* bcnt    = (int*)alloc(8 * NBKT);
    int* bstart  = (int*)alloc(8 * (NBKT + 1));
    int* bcur    = (int*)alloc(8 * NBKT);
    unsigned* recs = (unsigned*)alloc((size_t)8 * EE);
    unsigned short* sortedU = (unsigned short*)alloc((size_t)4 * EE);

    const float* WtEv = Wt;
    const float* WtEc = Wt + 8192;

    Ptr8 srcP, dstP;
    srcP.p[0] = mp_var;            dstP.p[0] = mp_var + EE;
    srcP.p[1] = mp_var + 2 * EE;   dstP.p[1] = mp_var + 3 * EE;
    srcP.p[2] = mp_cls;            dstP.p[2] = mp_cls + EE;
    srcP.p[3] = mp_cls + 2 * EE;   dstP.p[3] = mp_cls + 3 * EE;
    srcP.p[4] = adj_pos;           dstP.p[4] = adj_pos + EE;
    srcP.p[5] = adj_pos + EE;      dstP.p[5] = adj_pos;
    srcP.p[6] = adj_neg;           dstP.p[6] = adj_neg + EE;
    srcP.p[7] = adj_neg + EE;      dstP.p[7] = adj_neg;

    MArgs ma;
    ma.w[0] = sv_W;           ma.al[0] = sv_al;        ma.ar[0] = sv_ar;
    ma.w[1] = sv_W + 16384;   ma.al[1] = sv_al + 512;  ma.ar[1] = sv_ar + 512;
    ma.w[2] = sc_W;           ma.al[2] = sc_al;        ma.ar[2] = sc_ar;
    ma.w[3] = sc_W + 16384;   ma.al[3] = sc_al + 512;  ma.ar[3] = sc_ar + 512;
    ma.w[4] = cp_Wl;          ma.al[4] = cp_al;        ma.ar[4] = cp_ar;
    ma.w[5] = cp_Wr;          ma.al[5] = cp_al;        ma.ar[5] = cp_ar;
    ma.w[6] = cn_Wl;          ma.al[6] = cn_al;        ma.ar[6] = cn_ar;
    ma.w[7] = cn_Wr;          ma.al[7] = cn_al;        ma.ar[7] = cn_ar;

    // ---- two-level bucket sort of all 8 edge lists ----
    hipMemsetAsync(bcnt, 0, 8 * NBKT * sizeof(int), stream);
    bucket_count<<<8 * PA_B, 256, 0, stream>>>(dstP, bcnt);
    bucket_scan<<<8, 256, 0, stream>>>(bcnt, bstart, bcur);
    bucket_place<<<8 * PA_B, 256, 0, stream>>>(srcP, dstP, bcur, recs);
    bucket_final<<<8 * NBKT, 256, 0, stream>>>(recs, bstart, starts8, counts8, sortedU);

    prep_all<<<136, 256, 0, stream>>>(W_var_emb, W_cls_emb, Wt, ma, Mbuf, Wbf);

    EmbArgs Ev = { x_var, WtEv, ln_var_g, ln_var_b, var_pw, sv_b, F, C };
    EmbArgs Ec = { x_cls, WtEc, ln_cls_g, ln_cls_b, cls_pw, sc_b, G, D };
    embed_ln2<<<2 * (NN / 8), 128, 0, stream>>>(Ev, Ec, NN / 8);

    const int PB = (NN + 31) / 32;   // 1563 blocks, 32 rows each
    const int AB = NN / 8;           // 6250 chunks of 8 dsts per pair-set

    // ---- self attention: BOTH sides' projections in one launch ----
    ProjArgs Ps0 = { C, Wbf + 0 * 16384, Wbf + 1 * 16384, Mbuf + 0 * 1024, Mbuf + 1 * 1024,
                     B1, B2, (float4*)dl, (float4*)dr, (float4*)dl2, (float4*)dr2 };
    ProjArgs Ps1 = { D, Wbf + 2 * 16384, Wbf + 3 * 16384, Mbuf + 2 * 1024, Mbuf + 3 * 1024,
                     Pc, Pd, (float4*)dl3, (float4*)dr3, (float4*)dl4, (float4*)dr4 };
    mfma_proj2<<<2 * PB, 256, 0, stream>>>(Ps0, Ps1, PB);

    // ---- self aggregation: both sides in one launch ----
    {
        SegArg VA, VB, CA, CB;
        VA.starts = starts8 + 0 * NN; VA.counts = counts8 + 0 * NN;
        VA.srt = sortedU + (size_t)0 * EE;
        VA.adst = dl;  VA.asrc = dr;  VA.feats = B1; VA.pw = var_pw; VA.pwi = 0; VA.hasLoop = 1;
        VB.starts = starts8 + 1 * NN; VB.counts = counts8 + 1 * NN;
        VB.srt = sortedU + (size_t)1 * EE;
        VB.adst = dl2; VB.asrc = dr2; VB.feats = B2; VB.pw = var_pw; VB.pwi = 1; VB.hasLoop = 1;
        CA.starts = starts8 + 2 * NN; CA.counts = counts8 + 2 * NN;
        CA.srt = sortedU + (size_t)2 * EE;
        CA.adst = dl3; CA.asrc = dr3; CA.feats = Pc; CA.pw = cls_pw; CA.pwi = 0; CA.hasLoop = 1;
        CB.starts = starts8 + 3 * NN; CB.counts = counts8 + 3 * NN;
        CB.srt = sortedU + (size_t)3 * EE;
        CB.adst = dl4; CB.asrc = dr4; CB.feats = Pd; CB.pw = cls_pw; CB.pwi = 1; CB.hasLoop = 1;
        agg_fused2<<<2 * AB, 256, 0, stream>>>(VA, VB, F, CA, CB, G, cp_b, cn_b, AB, 0);
    }

    // ---- cross attention: both projections in one launch (independent buffers) ----
    ProjArgs Pc0 = { F, Wbf + 4 * 16384, Wbf + 6 * 16384, Mbuf + 4 * 1024, Mbuf + 6 * 1024,
                     B1, Pc, (float4*)dl, (float4*)dr, (float4*)dl3, (float4*)dr3 };
    ProjArgs Pc1 = { G, Wbf + 5 * 16384, Wbf + 7 * 16384, Mbuf + 5 * 1024, Mbuf + 7 * 1024,
                     B2, Pd, (float4*)dl2, (float4*)dr2, (float4*)dl4, (float4*)dr4 };
    mfma_proj2<<<2 * PB, 256, 0, stream>>>(Pc0, Pc1, PB);

    // ---- cross aggregation: both outputs in one launch ----
    {
        SegArg OA, OB, PA, PBs;
        OA.starts = starts8 + 4 * NN; OA.counts = counts8 + 4 * NN;
        OA.srt = sortedU + (size_t)4 * EE;
        OA.adst = dl;  OA.asrc = dr2; OA.feats = B2; OA.pw = nullptr; OA.pwi = 0; OA.hasLoop = 0;
        OB.starts = starts8 + 6 * NN; OB.counts = counts8 + 6 * NN;
        OB.srt = sortedU + (size_t)6 * EE;
        OB.adst = dl3; OB.asrc = dr4; OB.feats = Pd; OB.pw = nullptr; OB.pwi = 0; OB.hasLoop = 0;
        PA.starts = starts8 + 5 * NN; PA.counts = counts8 + 5 * NN;
        PA.srt = sortedU + (size_t)5 * EE;
        PA.adst = dl2; PA.asrc = dr;  PA.feats = B1; PA.pw = nullptr; PA.pwi = 0; PA.hasLoop = 0;
        PBs.starts = starts8 + 7 * NN; PBs.counts = counts8 + 7 * NN;
        PBs.srt = sortedU + (size_t)7 * EE;
        PBs.adst = dl4; PBs.asrc = dr3; PBs.feats = Pc; PBs.pw = nullptr; PBs.pwi = 0; PBs.hasLoop = 0;
        agg_fused2<<<2 * AB, 256, 0, stream>>>(OA, OB, out0, PA, PBs, out1, cp_b, cn_b, AB, 1);
    }
}